// Round 12
// baseline (504.968 us; speedup 1.0000x reference)
//
#include <hip/hip_runtime.h>
#include <hip/hip_bf16.h>
#include <cstdint>
#include <cstddef>

// Problem dims (fixed)
#define BB 16
#define LL 2048
#define MM (BB * LL)   // 32768 rows
#define KK 1024        // inner dim
#define HH 1024        // hidden per gate

typedef __attribute__((ext_vector_type(8))) short bf16x8;
typedef __attribute__((ext_vector_type(4))) float f32x4;

// ---------- fp32 -> bf16 (RNE) ----------
__device__ __forceinline__ unsigned short f2bf(float f) {
    unsigned u = __builtin_bit_cast(unsigned, f);
    u += 0x7fffu + ((u >> 16) & 1u);
    return (unsigned short)(u >> 16);
}

__global__ void cvt_f32_to_bf16(const float* __restrict__ in,
                                unsigned short* __restrict__ out, int n8) {
    int i = blockIdx.x * blockDim.x + threadIdx.x;
    if (i >= n8) return;
    const float4* p = reinterpret_cast<const float4*>(in) + (size_t)i * 2;
    float4 v0 = p[0];
    float4 v1 = p[1];
    union { unsigned short us[8]; uint4 v; } o;
    o.us[0] = f2bf(v0.x); o.us[1] = f2bf(v0.y);
    o.us[2] = f2bf(v0.z); o.us[3] = f2bf(v0.w);
    o.us[4] = f2bf(v1.x); o.us[5] = f2bf(v1.y);
    o.us[6] = f2bf(v1.z); o.us[7] = f2bf(v1.w);
    reinterpret_cast<uint4*>(out)[i] = o.v;
}

// ---------- mask scan ----------
__global__ __launch_bounds__(1024) void scan_mask(const int* __restrict__ mask,
                                                  int* __restrict__ rows,
                                                  int* __restrict__ Na) {
    __shared__ int psum[1024];
    const int t = threadIdx.x;
    const int base = t * 32;
    int m[32];
    int cnt = 0;
#pragma unroll
    for (int i = 0; i < 32; ++i) { m[i] = mask[base + i]; cnt += (m[i] != 0); }
    psum[t] = cnt;
    __syncthreads();
    for (int off = 1; off < 1024; off <<= 1) {
        int v = (t >= off) ? psum[t - off] : 0;
        __syncthreads();
        psum[t] += v;
        __syncthreads();
    }
    int offset = psum[t] - cnt;
#pragma unroll
    for (int i = 0; i < 32; ++i) {
        if (m[i]) rows[offset++] = base + i;
    }
    if (t == 1023) *Na = psum[1023];
}

// ---------- gather active rows of x, f32 -> bf16 ----------
__global__ __launch_bounds__(256) void gather_cvt(const float* __restrict__ x,
                                                  const int* __restrict__ rows,
                                                  const int* __restrict__ Na,
                                                  unsigned short* __restrict__ xbf) {
    const int j = blockIdx.x;
    if (j >= *Na) return;
    const int r = rows[j];
    const float4 v = reinterpret_cast<const float4*>(x + (size_t)r * KK)[threadIdx.x];
    ushort4 o;
    o.x = f2bf(v.x); o.y = f2bf(v.y); o.z = f2bf(v.z); o.w = f2bf(v.w);
    reinterpret_cast<ushort4*>(xbf + (size_t)j * KK)[threadIdx.x] = o;
}

// ---------- exact zeros for masked-out output rows ----------
__global__ __launch_bounds__(256) void zero_masked(const int* __restrict__ mask,
                                                   float* __restrict__ out) {
    const int m = blockIdx.x;
    if (mask[m] != 0) return;
    const int bb = m >> 11;
    const int ll = m & 2047;
    float4 z = {0.f, 0.f, 0.f, 0.f};
    reinterpret_cast<float4*>(out + ((size_t)ll * BB + bb) * HH)[threadIdx.x] = z;
}

// ---------- async global->LDS, 16B per lane ----------
__device__ __forceinline__ void gload16(const unsigned short* g, unsigned short* l) {
    __builtin_amdgcn_global_load_lds(
        (const __attribute__((address_space(1))) unsigned int*)g,
        (__attribute__((address_space(3))) unsigned int*)l,
        16, 0, 0);
}

#define WAITVM4  asm volatile("s_waitcnt vmcnt(4)" ::: "memory")
#define SB       __builtin_amdgcn_sched_barrier(0)
#define BAR      __builtin_amdgcn_s_barrier()

// ---------- fused GEMM + GRU gating: R6 skeleton, A via global->register ----------
// BM=128, BN=64 x 3 gates, BK=32, 256 threads (4 waves, 2M x 2N).
// Pipe analysis (R11 post-mortem): with A+B both in LDS, per CU-tile-pair the
// LDS pipe (80 ds_read_b128 x 12cy = 960cy) equals the MFMA pipe (192 x 4.85
// = 931cy) -> MfmaUtil can't exceed ~50% regardless of schedule (5 schedule
// variants all neutral). Fix: A fragments (only 2-way reuse; wc-twin waves
// read IDENTICAL addresses -> L1 twin-hit) load straight from global into
// registers, one tile ahead (afA/afB, static names). LDS holds only B.
// ds_reads: 10 -> 6 per wave-tile (LDS pipe ~576cy, now sub-dominant).
// LDS: 2 buffers x 6144 shorts (12KB) = 24KB. Staging 3 gload_lds per tile;
// end-of-tile drain vmcnt(4) = confirm the 3 B's, leave the 4 A-reg loads
// in flight (compiler inserts their waits at first use next tile).
// Swizzle (B): slot s of row r holds chunk s^((r>>1)&3) (verified 0-conflict
// R7-R11); linear gload dest + inverse-swizzled global source (rule #21).
// WAR with 1 barrier/tile: buf written at tile kt was last read at kt-1, and
// those ds_reads completed (lgkm-waited) before BAR(kt-1) (validated R11).
template <int MODE>
__global__ __launch_bounds__(256, 2) void gru_layer(
    const unsigned short* __restrict__ A,
    const unsigned short* __restrict__ W,
    const float* __restrict__ b_ih,
    const float* __restrict__ b_hh,
    const int* __restrict__ rows,
    const int* __restrict__ Na_p,
    unsigned short* __restrict__ out_bf,
    float* __restrict__ out_f) {
    __shared__ unsigned short lds[2][6144];  // 24576 B (B operand only)

    const int Na = *Na_p;
    const int m0 = blockIdx.x * 128;
    if (m0 >= Na) return;
    const int n0 = blockIdx.y * 64;

    const int tid  = threadIdx.x;
    const int lane = tid & 63;
    const int wid  = tid >> 6;
    const int wr   = wid >> 1;  // 0..1
    const int wc   = wid & 1;   // 0..1

    // --- B staging: thread t covers row t>>2 (0..63 per unit), slot t&3 ---
    const int trow = tid >> 2;
    const int tcol = ((tid & 3) ^ ((trow >> 1) & 3)) * 8;    // inverse-swizzled k
    const unsigned short* b0 = W + (size_t)(0 * HH + n0 + trow) * KK + tcol;
    const unsigned short* b1 = W + (size_t)(1 * HH + n0 + trow) * KK + tcol;
    const unsigned short* b2 = W + (size_t)(2 * HH + n0 + trow) * KK + tcol;

#define STAGE(kt, c) do {                                        \
        const int _o = (kt) * 32;                                \
        unsigned short* _L = &lds[(c)][wid * 512];               \
        gload16(b0 + _o, _L + 0 * 2048);                         \
        gload16(b1 + _o, _L + 1 * 2048);                         \
        gload16(b2 + _o, _L + 2 * 2048);                         \
    } while (0)

    // --- A fragment global pointers: lane l -> row base+ (l&15), k-chunk (l>>4)*8 ---
    const int l15 = lane & 15;
    const unsigned short* aptr[4];
#pragma unroll
    for (int mf = 0; mf < 4; ++mf) {
        int r = m0 + wr * 64 + mf * 16 + l15;
        if (r >= Na) r = Na - 1;
        aptr[mf] = A + (size_t)r * KK + (lane >> 4) * 8;
    }
#define LOADA(dst, kt) do {                                                    \
        _Pragma("unroll") for (int mf = 0; mf < 4; ++mf)                       \
            dst[mf] = *reinterpret_cast<const bf16x8*>(aptr[mf] + (kt) * 32);  \
    } while (0)

    // --- B read offsets (swizzled): row = wc*32 + nf*16 + l15, chunk = lane>>4 ---
    const int akp = (((lane >> 4) ^ (lane >> 1)) & 3) << 3;   // shorts
    int boff[2];
#pragma unroll
    for (int nf = 0; nf < 2; ++nf)
        boff[nf] = (wc * 32 + nf * 16 + l15) * 32 + akp;

    f32x4 accr[4][2] = {};
    f32x4 accz[4][2] = {};
    f32x4 accn[4][2] = {};
    bf16x8 afA[4], afB[4];

#define COMPUTE(Lp, af) do {                                                      \
        _Pragma("unroll") for (int nf = 0; nf < 2; ++nf) {                        \
            bf16x8 br  = *reinterpret_cast<const bf16x8*>(&(Lp)[boff[nf]]);       \
            bf16x8 bz  = *reinterpret_cast<const bf16x8*>(&(Lp)[boff[nf] + 2048]);\
            bf16x8 bnn = *reinterpret_cast<const bf16x8*>(&(Lp)[boff[nf] + 4096]);\
            __builtin_amdgcn_s_setprio(1);                                        \
            _Pragma("unroll") for (int mf = 0; mf < 4; ++mf) {                    \
                accr[mf][nf] = __builtin_amdgcn_mfma_f32_16x16x32_bf16(           \
                    af[mf], br,  accr[mf][nf], 0, 0, 0);                          \
                accz[mf][nf] = __builtin_amdgcn_mfma_f32_16x16x32_bf16(           \
                    af[mf], bz,  accz[mf][nf], 0, 0, 0);                          \
                accn[mf][nf] = __builtin_amdgcn_mfma_f32_16x16x32_bf16(           \
                    af[mf], bnn, accn[mf][nf], 0, 0, 0);                          \
            }                                                                     \
            __builtin_amdgcn_s_setprio(0);                                        \
        }                                                                         \
    } while (0)

    // prologue: stage B(0), load A(0) regs; vmcnt(4) retires the 3 B's only
    STAGE(0, 0);
    LOADA(afA, 0);
    WAITVM4; BAR; SB;

#pragma unroll 1
    for (int kt = 0; kt < 30; kt += 2) {
        // even tile kt: buf0 + afA; prefetch kt+1
        STAGE(kt + 1, 1);
        LOADA(afB, kt + 1);
        COMPUTE(lds[0], afA);
        WAITVM4; BAR; SB;      // retire B(kt+1); A(kt+1) stays in flight
        // odd tile kt+1: buf1 + afB; prefetch kt+2
        STAGE(kt + 2, 0);
        LOADA(afA, kt + 2);
        COMPUTE(lds[1], afB);
        WAITVM4; BAR; SB;
    }
    // tile 30: prefetch 31, compute buf0/afA
    STAGE(31, 1);
    LOADA(afB, 31);
    COMPUTE(lds[0], afA);
    WAITVM4; BAR; SB;
    // tile 31: compute buf1/afB (compiler waits remaining vmcnt for afB)
    COMPUTE(lds[1], afB);

    // --- epilogue: gating; C/D layout col = lane&15, row = (lane>>4)*4 + j ---
#pragma unroll
    for (int nf = 0; nf < 2; ++nf) {
        const int col = n0 + wc * 32 + nf * 16 + l15;
        const float br_b = b_ih[col] + b_hh[col];
        const float bz_b = b_ih[HH + col] + b_hh[HH + col];
        const float bn_i = b_ih[2 * HH + col];
        const float bn_h = b_hh[2 * HH + col];
#pragma unroll
        for (int mf = 0; mf < 4; ++mf) {
#pragma unroll
            for (int j = 0; j < 4; ++j) {
                const int row = m0 + wr * 64 + mf * 16 + (lane >> 4) * 4 + j;
                if (row >= Na) continue;
                const float r = 1.f / (1.f + __expf(-(accr[mf][nf][j] + br_b)));
                const float z = 1.f / (1.f + __expf(-(accz[mf][nf][j] + bz_b)));
                const float xn = accn[mf][nf][j] + bn_i + r * bn_h;
                // stable tanh: exp of negative arg only (no overflow)
                const float t  = __expf(-2.f * fabsf(xn));
                const float nv = copysignf((1.f - t) / (1.f + t), xn);
                const float h = (1.f - z) * nv;
                if (MODE == 0) {
                    out_bf[(size_t)row * HH + col] = f2bf(h);
                } else {
                    const int orig = rows[row];
                    const int bb = orig >> 11;
                    const int ll = orig & 2047;
                    out_f[((size_t)ll * BB + bb) * HH + col] = h;
                }
            }
        }
    }
#undef STAGE
#undef LOADA
#undef COMPUTE
}

extern "C" void kernel_launch(void* const* d_in, const int* in_sizes, int n_in,
                              void* d_out, int out_size, void* d_ws, size_t ws_size,
                              hipStream_t stream) {
    const float* x   = (const float*)d_in[0];
    const int*   msk = (const int*)d_in[1];
    const float* W0  = (const float*)d_in[2];
    const float* bi0 = (const float*)d_in[4];
    const float* bh0 = (const float*)d_in[5];
    const float* W1  = (const float*)d_in[6];
    const float* bi1 = (const float*)d_in[8];
    const float* bh1 = (const float*)d_in[9];
    float* out = (float*)d_out;

    char* ws = (char*)d_ws;
    unsigned short* xbf  = (unsigned short*)ws;                  // 67,108,864 B (worst case)
    unsigned short* h1bf = (unsigned short*)(ws + 67108864);     // 67,108,864 B (worst case)
    unsigned short* w0bf = (unsigned short*)(ws + 134217728);    //  6,291,456 B
    unsigned short* w1bf = (unsigned short*)(ws + 140509184);    //  6,291,456 B
    int* rows = (int*)(ws + 146800640);                          //    131,072 B
    int* Na   = (int*)(ws + 146931712);                          //          4 B

    scan_mask<<<1, 1024, 0, stream>>>(msk, rows, Na);

    cvt_f32_to_bf16<<<1536, 256, 0, stream>>>(W0, w0bf, 3 * HH * KK / 8);
    cvt_f32_to_bf16<<<1536, 256, 0, stream>>>(W1, w1bf, 3 * HH * KK / 8);

    zero_masked<<<MM, 256, 0, stream>>>(msk, out);
    gather_cvt<<<MM, 256, 0, stream>>>(x, rows, Na, xbf);

    dim3 grid(MM / 128, HH / 64);  // (256, 16) worst case; blocks past Na exit
    gru_layer<0><<<grid, 256, 0, stream>>>(xbf, w0bf, bi0, bh0, rows, Na, h1bf, nullptr);
    gru_layer<1><<<grid, 256, 0, stream>>>(h1bf, w1bf, bi1, bh1, rows, Na, nullptr, out);
}

// Round 15
// 349.916 us; speedup vs baseline: 1.4431x; 1.4431x over previous
//
#include <hip/hip_runtime.h>
#include <hip/hip_bf16.h>
#include <cstdint>
#include <cstddef>

// Problem dims (fixed)
#define BB 16
#define LL 2048
#define MM (BB * LL)   // 32768 rows
#define KK 1024        // inner dim
#define HH 1024        // hidden per gate

typedef __attribute__((ext_vector_type(8))) short bf16x8;
typedef __attribute__((ext_vector_type(4))) float f32x4;

// ---------- fp32 -> bf16 (RNE) ----------
__device__ __forceinline__ unsigned short f2bf(float f) {
    unsigned u = __builtin_bit_cast(unsigned, f);
    u += 0x7fffu + ((u >> 16) & 1u);
    return (unsigned short)(u >> 16);
}

// ---------- convert BOTH weight matrices in one launch ----------
__global__ __launch_bounds__(256) void cvt_w2(const float* __restrict__ w0,
                                              const float* __restrict__ w1,
                                              unsigned short* __restrict__ o0,
                                              unsigned short* __restrict__ o1,
                                              int n8each) {
    int i = blockIdx.x * blockDim.x + threadIdx.x;
    const float* in;
    unsigned short* out;
    if (i >= n8each) { in = w1; out = o1; i -= n8each; }
    else             { in = w0; out = o0; }
    const float4* p = reinterpret_cast<const float4*>(in) + (size_t)i * 2;
    float4 v0 = p[0];
    float4 v1 = p[1];
    union { unsigned short us[8]; uint4 v; } o;
    o.us[0] = f2bf(v0.x); o.us[1] = f2bf(v0.y);
    o.us[2] = f2bf(v0.z); o.us[3] = f2bf(v0.w);
    o.us[4] = f2bf(v1.x); o.us[5] = f2bf(v1.y);
    o.us[6] = f2bf(v1.z); o.us[7] = f2bf(v1.w);
    reinterpret_cast<uint4*>(out)[i] = o.v;
}

// ---------- mask scan ----------
__global__ __launch_bounds__(1024) void scan_mask(const int* __restrict__ mask,
                                                  int* __restrict__ rows,
                                                  int* __restrict__ Na) {
    __shared__ int psum[1024];
    const int t = threadIdx.x;
    const int base = t * 32;
    int m[32];
    int cnt = 0;
#pragma unroll
    for (int i = 0; i < 32; ++i) { m[i] = mask[base + i]; cnt += (m[i] != 0); }
    psum[t] = cnt;
    __syncthreads();
    for (int off = 1; off < 1024; off <<= 1) {
        int v = (t >= off) ? psum[t - off] : 0;
        __syncthreads();
        psum[t] += v;
        __syncthreads();
    }
    int offset = psum[t] - cnt;
#pragma unroll
    for (int i = 0; i < 32; ++i) {
        if (m[i]) rows[offset++] = base + i;
    }
    if (t == 1023) *Na = psum[1023];
}

// ---------- gather active rows of x, f32 -> bf16 (16 rows per block) ----------
__global__ __launch_bounds__(256) void gather_cvt(const float* __restrict__ x,
                                                  const int* __restrict__ rows,
                                                  const int* __restrict__ Na_p,
                                                  unsigned short* __restrict__ xbf) {
    const int Na = *Na_p;
    const int t = threadIdx.x;
#pragma unroll 1
    for (int rr = 0; rr < 16; ++rr) {
        const int j = blockIdx.x * 16 + rr;
        if (j >= Na) return;
        const int r = rows[j];
        const float4 v = reinterpret_cast<const float4*>(x + (size_t)r * KK)[t];
        ushort4 o;
        o.x = f2bf(v.x); o.y = f2bf(v.y); o.z = f2bf(v.z); o.w = f2bf(v.w);
        reinterpret_cast<ushort4*>(xbf + (size_t)j * KK)[t] = o;
    }
}

// ---------- exact zeros for masked-out output rows (16 rows per block) ----------
__global__ __launch_bounds__(256) void zero_masked(const int* __restrict__ mask,
                                                   float* __restrict__ out) {
    const int t = threadIdx.x;
    const float4 z = {0.f, 0.f, 0.f, 0.f};
#pragma unroll 1
    for (int rr = 0; rr < 16; ++rr) {
        const int m = blockIdx.x * 16 + rr;
        if (mask[m] != 0) continue;
        const int bb = m >> 11;
        const int ll = m & 2047;
        reinterpret_cast<float4*>(out + ((size_t)ll * BB + bb) * HH)[t] = z;
    }
}

// ---------- async global->LDS, 16B per lane (offset=0 ONLY; R13: nonzero = NaN) ----------
__device__ __forceinline__ void gload16(const unsigned short* g, unsigned short* l) {
    __builtin_amdgcn_global_load_lds(
        (const __attribute__((address_space(1))) unsigned int*)g,
        (__attribute__((address_space(3))) unsigned int*)l,
        16, 0, 0);
}

#define WAITVM0  asm volatile("s_waitcnt vmcnt(0)" ::: "memory")
#define SB       __builtin_amdgcn_sched_barrier(0)
#define BAR      __builtin_amdgcn_s_barrier()

// ---------- fused GEMM + GRU gating: R8-verified kernel, BYTE-IDENTICAL ----------
// (9 structural variants bracketed this at 157us/layer; R13/R14 retired the
//  nonzero-gload-offset and 32x32-MFMA branches as unsafe. Do not modify.)
// BM=128, BN=64 x 3 gates, BK=32, 256 threads (4 waves, 2M x 2N).
// 2 buffers x 10240 shorts (20KB) = 40KB LDS.
// Swizzle: 16B slot s of row r holds k-chunk s ^ ((r>>1)&3) (0-conflict, R8);
// linear gload dest + inverse-swizzled global source (rule #21).
template <int MODE>
__global__ __launch_bounds__(256, 3) void gru_layer(
    const unsigned short* __restrict__ A,
    const unsigned short* __restrict__ W,
    const float* __restrict__ b_ih,
    const float* __restrict__ b_hh,
    const int* __restrict__ rows,
    const int* __restrict__ Na_p,
    unsigned short* __restrict__ out_bf,
    float* __restrict__ out_f) {
    __shared__ unsigned short lds[2][10240];  // 40960 B

    const int Na = *Na_p;
    const int m0 = blockIdx.x * 128;
    if (m0 >= Na) return;
    const int n0 = blockIdx.y * 64;

    const int tid  = threadIdx.x;
    const int lane = tid & 63;
    const int wid  = tid >> 6;
    const int wr   = wid >> 1;  // 0..1
    const int wc   = wid & 1;   // 0..1

    // --- staging: thread t -> unit-linear slot t*16B = (row t/4, slot t&3) ---
    const int trow = tid >> 2;
    const int tcol = ((tid & 3) ^ ((trow >> 1) & 3)) * 8;    // inverse-swizzled k
    int r0 = m0 + trow;        if (r0 >= Na) r0 = Na - 1;
    int r1 = m0 + 64 + trow;   if (r1 >= Na) r1 = Na - 1;
    const unsigned short* a0 = A + (size_t)r0 * KK + tcol;
    const unsigned short* a1 = A + (size_t)r1 * KK + tcol;
    const unsigned short* b0 = W + (size_t)(0 * HH + n0 + trow) * KK + tcol;
    const unsigned short* b1 = W + (size_t)(1 * HH + n0 + trow) * KK + tcol;
    const unsigned short* b2 = W + (size_t)(2 * HH + n0 + trow) * KK + tcol;

#define STAGE(kt, c) do {                                        \
        const int _o = (kt) * 32;                                \
        unsigned short* _L = &lds[(c)][wid * 512];               \
        gload16(a0 + _o, _L + 0 * 2048);                         \
        gload16(a1 + _o, _L + 1 * 2048);                         \
        gload16(b0 + _o, _L + 2 * 2048);                         \
        gload16(b1 + _o, _L + 3 * 2048);                         \
        gload16(b2 + _o, _L + 4 * 2048);                         \
    } while (0)

    // --- read offsets: lane l, row base+l15, chunk c=l>>4 at slot c^((row>>1)&3) ---
    const int l15 = lane & 15;
    const int akp = (((lane >> 4) ^ (lane >> 1)) & 3) << 3;   // shorts
    int aoff[4], boff[2];
#pragma unroll
    for (int mf = 0; mf < 4; ++mf)
        aoff[mf] = (wr * 64 + mf * 16 + l15) * 32 + akp;
#pragma unroll
    for (int nf = 0; nf < 2; ++nf)
        boff[nf] = 4096 + (wc * 32 + nf * 16 + l15) * 32 + akp;

    f32x4 accr[4][2] = {};
    f32x4 accz[4][2] = {};
    f32x4 accn[4][2] = {};

#define COMPUTE(Lp) do {                                                          \
        bf16x8 af[4];                                                             \
        _Pragma("unroll") for (int mf = 0; mf < 4; ++mf)                          \
            af[mf] = *reinterpret_cast<const bf16x8*>(&(Lp)[aoff[mf]]);           \
        _Pragma("unroll") for (int nf = 0; nf < 2; ++nf) {                        \
            bf16x8 br  = *reinterpret_cast<const bf16x8*>(&(Lp)[boff[nf]]);       \
            bf16x8 bz  = *reinterpret_cast<const bf16x8*>(&(Lp)[boff[nf] + 2048]);\
            bf16x8 bnn = *reinterpret_cast<const bf16x8*>(&(Lp)[boff[nf] + 4096]);\
            __builtin_amdgcn_s_setprio(1);                                        \
            _Pragma("unroll") for (int mf = 0; mf < 4; ++mf) {                    \
                accr[mf][nf] = __builtin_amdgcn_mfma_f32_16x16x32_bf16(           \
                    af[mf], br,  accr[mf][nf], 0, 0, 0);                          \
                accz[mf][nf] = __builtin_amdgcn_mfma_f32_16x16x32_bf16(           \
                    af[mf], bz,  accz[mf][nf], 0, 0, 0);                          \
                accn[mf][nf] = __builtin_amdgcn_mfma_f32_16x16x32_bf16(           \
                    af[mf], bnn, accn[mf][nf], 0, 0, 0);                          \
            }                                                                     \
            __builtin_amdgcn_s_setprio(0);                                        \
        }                                                                         \
    } while (0)

    // prologue: stage tile 0, drain, barrier
    STAGE(0, 0);
    WAITVM0; BAR; SB;

    int cur = 0;
#pragma unroll 1
    for (int kt = 0; kt < 31; ++kt) {
        STAGE(kt + 1, cur ^ 1);          // issue next-tile loads FIRST
        const unsigned short* L = &lds[cur][0];
        COMPUTE(L);                       // ds_read + MFMA hide the load latency
        WAITVM0; BAR; SB;                 // drain after compute, once per tile
        cur ^= 1;
    }
    {   // peeled last tile: no staging
        const unsigned short* L = &lds[cur][0];
        COMPUTE(L);
    }

    // --- epilogue: gating; C/D layout col = lane&15, row = (lane>>4)*4 + j ---
#pragma unroll
    for (int nf = 0; nf < 2; ++nf) {
        const int col = n0 + wc * 32 + nf * 16 + l15;
        const float br_b = b_ih[col] + b_hh[col];
        const float bz_b = b_ih[HH + col] + b_hh[HH + col];
        const float bn_i = b_ih[2 * HH + col];
        const float bn_h = b_hh[2 * HH + col];
#pragma unroll
        for (int mf = 0; mf < 4; ++mf) {
#pragma unroll
            for (int j = 0; j < 4; ++j) {
                const int row = m0 + wr * 64 + mf * 16 + (lane >> 4) * 4 + j;
                if (row >= Na) continue;
                const float r = 1.f / (1.f + __expf(-(accr[mf][nf][j] + br_b)));
                const float z = 1.f / (1.f + __expf(-(accz[mf][nf][j] + bz_b)));
                const float n = tanhf(accn[mf][nf][j] + bn_i + r * bn_h);
                const float h = (1.f - z) * n;
                if (MODE == 0) {
                    out_bf[(size_t)row * HH + col] = f2bf(h);
                } else {
                    const int orig = rows[row];
                    const int bb = orig >> 11;
                    const int ll = orig & 2047;
                    out_f[((size_t)ll * BB + bb) * HH + col] = h;
                }
            }
        }
    }
#undef STAGE
#undef COMPUTE
}

extern "C" void kernel_launch(void* const* d_in, const int* in_sizes, int n_in,
                              void* d_out, int out_size, void* d_ws, size_t ws_size,
                              hipStream_t stream) {
    const float* x   = (const float*)d_in[0];
    const int*   msk = (const int*)d_in[1];
    const float* W0  = (const float*)d_in[2];
    const float* bi0 = (const float*)d_in[4];
    const float* bh0 = (const float*)d_in[5];
    const float* W1  = (const float*)d_in[6];
    const float* bi1 = (const float*)d_in[8];
    const float* bh1 = (const float*)d_in[9];
    float* out = (float*)d_out;

    char* ws = (char*)d_ws;
    unsigned short* xbf  = (unsigned short*)ws;                  // 67,108,864 B (worst case)
    unsigned short* h1bf = (unsigned short*)(ws + 67108864);     // 67,108,864 B (worst case)
    unsigned short* w0bf = (unsigned short*)(ws + 134217728);    //  6,291,456 B
    unsigned short* w1bf = (unsigned short*)(ws + 140509184);    //  6,291,456 B
    int* rows = (int*)(ws + 146800640);                          //    131,072 B
    int* Na   = (int*)(ws + 146931712);                          //          4 B

    scan_mask<<<1, 1024, 0, stream>>>(msk, rows, Na);

    // both weight conversions in one launch (3072 blocks; first half W0)
    cvt_w2<<<3072, 256, 0, stream>>>(W0, W1, w0bf, w1bf, 3 * HH * KK / 8);

    // exact zeros for masked-out output rows; 16 rows per block (G11 batching)
    zero_masked<<<MM / 16, 256, 0, stream>>>(msk, out);

    // gather + convert active rows of x; 16 rows per block
    gather_cvt<<<MM / 16, 256, 0, stream>>>(x, rows, Na, xbf);

    dim3 grid(MM / 128, HH / 64);  // (256, 16) worst case; blocks past Na exit
    gru_layer<0><<<grid, 256, 0, stream>>>(xbf, w0bf, bi0, bh0, rows, Na, h1bf, nullptr);
    gru_layer<1><<<grid, 256, 0, stream>>>(h1bf, w1bf, bi1, bh1, rows, Na, nullptr, out);
}